// Round 11
// baseline (2604.993 us; speedup 1.0000x reference)
//
#include <hip/hip_runtime.h>
#include <math.h>

#define SEQ 256
#define BATCH 64
#define HID 1024
#define VOCAB 4000
#define H3 (3 * HID)
#define HSLICE (BATCH * HID)

typedef __attribute__((ext_vector_type(8))) short short8;
typedef __attribute__((ext_vector_type(4))) float f32x4;

__device__ inline unsigned short f2bf(float x) {
    unsigned int u = __builtin_bit_cast(unsigned int, x);
    unsigned int r = (u + 0x7fffu + ((u >> 16) & 1u)) >> 16;   // RNE
    return (unsigned short)r;
}
__device__ inline float bf2f(unsigned short h) {
    unsigned int u = ((unsigned int)h) << 16;
    return __builtin_bit_cast(float, u);
}

// ---------------------------------------------------------------------------
// Split f32 arrays into bf16 hi/lo pairs. h0 goes into slice 0 of the
// h-history (so the persistent kernel has no t==0 special case).
// ---------------------------------------------------------------------------
__global__ __launch_bounds__(256) void split_kernel(
    const float* __restrict__ W_hh, const float* __restrict__ W_out,
    const float* __restrict__ h0,
    unsigned short* __restrict__ whh_hi, unsigned short* __restrict__ whh_lo,
    unsigned short* __restrict__ wout_hi, unsigned short* __restrict__ wout_lo,
    unsigned short* __restrict__ h0_hi, unsigned short* __restrict__ h0_lo)
{
    const int NW = 3 * HID * HID;
    const int NO = VOCAB * HID;
    const int NH = BATCH * HID;
    const int total = NW + NO + NH;
    for (int i = blockIdx.x * blockDim.x + threadIdx.x; i < total;
         i += gridDim.x * blockDim.x) {
        const float* src; unsigned short *dh, *dl; int off;
        if (i < NW)           { src = W_hh;  dh = whh_hi;  dl = whh_lo;  off = i; }
        else if (i < NW + NO) { src = W_out; dh = wout_hi; dl = wout_lo; off = i - NW; }
        else                  { src = h0;    dh = h0_hi;   dl = h0_lo;   off = i - NW - NO; }
        float x = src[off];
        unsigned short hi = f2bf(x);
        dh[off] = hi;
        dl[off] = f2bf(x - bf2f(hi));
    }
}

// ---------------------------------------------------------------------------
// W_ih (3072 x 4000) -> W_ihT (4000 x 3072), 32x32 LDS tiles.
// ---------------------------------------------------------------------------
__global__ __launch_bounds__(256) void transpose_wih(
    const float* __restrict__ W_ih, float* __restrict__ W_ihT)
{
    __shared__ float tile[32][33];
    const int tx = threadIdx.x & 31;
    const int ty = threadIdx.x >> 5;          // 0..7
    const int r0 = blockIdx.y * 32;           // 3072-dim base
    const int c0 = blockIdx.x * 32;           // 4000-dim base
    #pragma unroll
    for (int k = 0; k < 4; ++k) {
        const int r = ty + k * 8;
        tile[r][tx] = W_ih[(size_t)(r0 + r) * VOCAB + c0 + tx];  // 4000%32==0
    }
    __syncthreads();
    #pragma unroll
    for (int k = 0; k < 4; ++k) {
        const int r = ty + k * 8;
        W_ihT[(size_t)(c0 + r) * H3 + r0 + tx] = tile[tx][r];
    }
}

__global__ void zero_barrier(int* b) {                    // 8192 ints (32 KB)
    b[blockIdx.x * 1024 + threadIdx.x] = 0;
}

// ---------------------------------------------------------------------------
// Persistent cooperative GRU: 128 blocks x 1024 threads, TWO chains/block.
// The GRU is independent per batch: the 4 mt-groups (16 batches each) are 4
// independent recurrence chains. Block (jt, p) handles chains mt=p and
// mt=p+2, alternating phases: while chain A's h-publication propagates
// through LLC, the block computes chain B's phase -> the producer->LLC->
// consumer hop (which was ~3 us/step of stall in round 10) is hidden under
// the sibling phase. Weights (shared by both chains) stay register-hoisted;
// sync stays p2p flags + agent-scope write-through h-stores (round 10).
// ---------------------------------------------------------------------------
__global__ __launch_bounds__(1024) void gru_persist(
    const unsigned short* __restrict__ whh_hi,
    const unsigned short* __restrict__ whh_lo,
    const float* __restrict__ W_ihT,
    const float* __restrict__ b_ih,
    const float* __restrict__ b_hh,
    const float* __restrict__ h0,
    const int* __restrict__ ids,
    unsigned short* ghi,                 // (SEQ+1) slices of 64x1024
    unsigned short* glo,
    float* hn_out,                       // d_out tail (64x1024)
    int* flag)                           // 256 flags, stride 32 ints
{
    __shared__ f32x4 red[16][3][64];     // [ksplit][gate][lane] = 48 KB

    const int tid = threadIdx.x;
    const int w   = tid >> 6;            // 0..15 (K-split)
    const int l   = tid & 63;
    const int bid = blockIdx.x;
    const int grp   = bid & 7;           // XCD (round-robin dispatch)
    const int local = bid >> 3;          // 0..15
    const int jt  = grp * 8 + (local >> 1);   // 0..63 (8 j-tiles per XCD)
    const int p   = local & 1;           // chain pair
    const int mt0 = p, mt1 = p + 2;      // this block's two chains
    const int j0  = jt * 16;
    const int col = l & 15, kg = l >> 4;

    const size_t arow0  = (size_t)(mt0 * 16 + col) * HID;
    const size_t arow1  = (size_t)(mt1 * 16 + col) * HID;
    const size_t brow_r = (size_t)(j0 + col) * HID;
    const size_t brow_z = (size_t)(HID + j0 + col) * HID;
    const size_t brow_n = (size_t)(2 * HID + j0 + col) * HID;
    const int kbase = w * 64 + kg * 8;

    // ---- hoist this wave's weight fragments into registers (48 VGPRs) ----
    short8 wr_h[2], wr_l[2], wz_h[2], wz_l[2], wn_h[2], wn_l[2];
    #pragma unroll
    for (int c = 0; c < 2; ++c) {
        const int ko = kbase + c * 32;
        wr_h[c] = *(const short8*)(whh_hi + brow_r + ko);
        wr_l[c] = *(const short8*)(whh_lo + brow_r + ko);
        wz_h[c] = *(const short8*)(whh_hi + brow_z + ko);
        wz_l[c] = *(const short8*)(whh_lo + brow_z + ko);
        wn_h[c] = *(const short8*)(whh_hi + brow_n + ko);
        wn_l[c] = *(const short8*)(whh_lo + brow_n + ko);
    }

    // epilogue persistent state: tid<256, 1 thread = 1 output (b, j) per chain
    const int bi = (tid >> 4) & 15;
    const int cj = tid & 15;
    const int ej = j0 + cj;
    const int eb0 = mt0 * 16 + bi, eb1 = mt1 * 16 + bi;
    float hreg0 = 0.f, xr0 = 0.f, xz0 = 0.f, xn0 = 0.f;
    float hreg1 = 0.f, xr1 = 0.f, xz1 = 0.f, xn1 = 0.f;
    float bihr = 0.f, bihz = 0.f, bihn = 0.f;
    float bhhr = 0.f, bhhz = 0.f, bhhn = 0.f;
    if (tid < 256) {
        hreg0 = h0[(size_t)eb0 * HID + ej];
        hreg1 = h0[(size_t)eb1 * HID + ej];
        bihr = b_ih[ej]; bihz = b_ih[HID + ej]; bihn = b_ih[2 * HID + ej];
        bhhr = b_hh[ej]; bhhz = b_hh[HID + ej]; bhhn = b_hh[2 * HID + ej];
        const float* x0 = W_ihT + (size_t)ids[eb0 * SEQ] * H3;
        const float* x1 = W_ihT + (size_t)ids[eb1 * SEQ] * H3;
        xr0 = x0[ej]; xz0 = x0[HID + ej]; xn0 = x0[2 * HID + ej];
        xr1 = x1[ej]; xz1 = x1[HID + ej]; xn1 = x1[2 * HID + ej];
    }
    const int lane = (bi >> 2) * 16 + cj;   // MFMA C-layout inverse
    const int reg  = bi & 3;

    const int myflag0 = (jt * 4 + mt0) * 32;
    const int myflag1 = (jt * 4 + mt1) * 32;
    const int pollj   = 4 * w + (l & 3);    // lanes 0-3 poll these j-tiles
    const int pollfl0 = (pollj * 4 + mt0) * 32;
    const int pollfl1 = (pollj * 4 + mt1) * 32;

// one chain phase: poll -> MFMA -> reduce -> gates -> WT store -> flag
#define PHASE(AROW, EB, HREG, XR, XZ, XN, MYFLAG, POLLFL)                     \
    {                                                                          \
        if (t > 0) {                                                           \
            if (l < 4) {                                                       \
                while (__hip_atomic_load(&flag[POLLFL], __ATOMIC_RELAXED,      \
                                         __HIP_MEMORY_SCOPE_AGENT) < t)        \
                    __builtin_amdgcn_s_sleep(1);                               \
            }                                                                  \
            asm volatile("" ::: "memory");                                     \
        }                                                                      \
        f32x4 accr = {0.f, 0.f, 0.f, 0.f};                                     \
        f32x4 accz = {0.f, 0.f, 0.f, 0.f};                                     \
        f32x4 accn = {0.f, 0.f, 0.f, 0.f};                                     \
        _Pragma("unroll")                                                      \
        for (int c = 0; c < 2; ++c) {                                          \
            const int ko = kbase + c * 32;                                     \
            short8 a_h = *(const short8*)(ah + (AROW) + ko);                   \
            short8 a_l = *(const short8*)(al + (AROW) + ko);                   \
            accr = __builtin_amdgcn_mfma_f32_16x16x32_bf16(a_h, wr_h[c], accr, 0, 0, 0); \
            accr = __builtin_amdgcn_mfma_f32_16x16x32_bf16(a_h, wr_l[c], accr, 0, 0, 0); \
            accr = __builtin_amdgcn_mfma_f32_16x16x32_bf16(a_l, wr_h[c], accr, 0, 0, 0); \
            accz = __builtin_amdgcn_mfma_f32_16x16x32_bf16(a_h, wz_h[c], accz, 0, 0, 0); \
            accz = __builtin_amdgcn_mfma_f32_16x16x32_bf16(a_h, wz_l[c], accz, 0, 0, 0); \
            accz = __builtin_amdgcn_mfma_f32_16x16x32_bf16(a_l, wz_h[c], accz, 0, 0, 0); \
            accn = __builtin_amdgcn_mfma_f32_16x16x32_bf16(a_h, wn_h[c], accn, 0, 0, 0); \
            accn = __builtin_amdgcn_mfma_f32_16x16x32_bf16(a_h, wn_l[c], accn, 0, 0, 0); \
            accn = __builtin_amdgcn_mfma_f32_16x16x32_bf16(a_l, wn_h[c], accn, 0, 0, 0); \
        }                                                                      \
        red[w][0][l] = accr;                                                   \
        red[w][1][l] = accz;                                                   \
        red[w][2][l] = accn;                                                   \
        __syncthreads();                                                       \
        if (tid < 256) {                                                       \
            float sr = 0.f, sz = 0.f, sn = 0.f;                                \
            _Pragma("unroll")                                                  \
            for (int kk = 0; kk < 16; ++kk) {                                  \
                sr += ((const float*)&red[kk][0][lane])[reg];                  \
                sz += ((const float*)&red[kk][1][lane])[reg];                  \
                sn += ((const float*)&red[kk][2][lane])[reg];                  \
            }                                                                  \
            const float xrv = (XR) + bihr;                                     \
            const float xzv = (XZ) + bihz;                                     \
            const float xnv = (XN) + bihn;                                     \
            const float rg = 1.f / (1.f + expf(-(xrv + sr + bhhr)));           \
            const float zg = 1.f / (1.f + expf(-(xzv + sz + bhhz)));           \
            const float ng = tanhf(xnv + rg * (sn + bhhn));                    \
            (HREG) = (1.f - zg) * ng + zg * (HREG);                            \
            const unsigned short hh = f2bf(HREG);                              \
            const unsigned short ll = f2bf((HREG) - bf2f(hh));                 \
            const unsigned int hh_n = (unsigned int)(unsigned short)           \
                __shfl_xor((int)hh, 1, 64);                                    \
            const unsigned int ll_n = (unsigned int)(unsigned short)           \
                __shfl_xor((int)ll, 1, 64);                                    \
            const size_t ho = (size_t)(t + 1) * HSLICE + (size_t)(EB) * HID + ej; \
            if ((cj & 1) == 0) {                                               \
                const unsigned int hp = (unsigned int)hh | (hh_n << 16);       \
                const unsigned int lp = (unsigned int)ll | (ll_n << 16);       \
                __hip_atomic_store((unsigned int*)ghi + (ho >> 1), hp,         \
                                   __ATOMIC_RELAXED, __HIP_MEMORY_SCOPE_AGENT);\
                __hip_atomic_store((unsigned int*)glo + (ho >> 1), lp,         \
                                   __ATOMIC_RELAXED, __HIP_MEMORY_SCOPE_AGENT);\
            }                                                                  \
            if (t + 1 < SEQ) {                                                 \
                const float* xrow = W_ihT + (size_t)ids[(EB) * SEQ + t + 1] * H3; \
                (XR) = xrow[ej]; (XZ) = xrow[HID + ej]; (XN) = xrow[2 * HID + ej]; \
            } else {                                                           \
                hn_out[(size_t)(EB) * HID + ej] = (HREG);                      \
            }                                                                  \
        }                                                                      \
        __syncthreads();                                                       \
        if (tid == 0) {                                                        \
            __hip_atomic_store(&flag[MYFLAG], t + 1, __ATOMIC_RELAXED,         \
                               __HIP_MEMORY_SCOPE_AGENT);                      \
        }                                                                      \
    }

    for (int t = 0; t < SEQ; ++t) {
        const unsigned short* ah = ghi + (size_t)t * HSLICE;   // h_{t-1}
        const unsigned short* al = glo + (size_t)t * HSLICE;
        PHASE(arow0, eb0, hreg0, xr0, xz0, xn0, myflag0, pollfl0)
        PHASE(arow1, eb1, hreg1, xr1, xz1, xn1, myflag1, pollfl1)
    }
#undef PHASE
}

// ---------------------------------------------------------------------------
// Output GEMM, split-bf16 MFMA. 1D grid 4096 blocks, XCD-aware stripes.
// ---------------------------------------------------------------------------
__global__ __launch_bounds__(256) void out_gemm_mfma(
    const unsigned short* __restrict__ Ahi_g,  // 16384 x 1024
    const unsigned short* __restrict__ Alo_g,
    const unsigned short* __restrict__ Bhi_g,  // 4000 x 1024
    const unsigned short* __restrict__ Blo_g,
    const float* __restrict__ bias,
    float* __restrict__ C)
{
    constexpr int BM = 128, BK = 32, LDK = 40;
    __shared__ unsigned short Ah[BM * LDK], Al[BM * LDK];
    __shared__ unsigned short Bh[BM * LDK], Bl[BM * LDK];

    const int tid = threadIdx.x;
    const int l = tid & 63, w = tid >> 6;
    const int wr = w >> 1, wc = w & 1;
    const int col = l & 15, kg = l >> 4;
    const int bid = blockIdx.x;
    const int xcd = bid & 7;
    const int q   = bid >> 3;
    const int yb  = xcd * 4 + (q >> 7);       // 0..31 (n-tile)
    const int xb  = q & 127;                  // 0..127 (m-tile)
    const int m0 = xb * BM;
    const int n0 = yb * BM;

    f32x4 acc[4][4];
    #pragma unroll
    for (int i = 0; i < 4; ++i)
        #pragma unroll
        for (int jt = 0; jt < 4; ++jt)
            acc[i][jt] = (f32x4){0.f, 0.f, 0.f, 0.f};

    for (int kc = 0; kc < HID; kc += BK) {
        __syncthreads();
        #pragma unroll
        for (int i = 0; i < 2; ++i) {
            const int idx = tid + i * 256;          // 0..511
            const int row = idx >> 2, kq = idx & 3;
            const int go = kc + kq * 8;
            *(short8*)(Ah + row * LDK + kq * 8) =
                *(const short8*)(Ahi_g + (size_t)(m0 + row) * HID + go);
            *(short8*)(Al + row * LDK + kq * 8) =
                *(const short8*)(Alo_g + (size_t)(m0 + row) * HID + go);
            const int n = n0 + row;
            short8 vh = {0,0,0,0,0,0,0,0}, vl = {0,0,0,0,0,0,0,0};
            if (n < VOCAB) {
                vh = *(const short8*)(Bhi_g + (size_t)n * HID + go);
                vl = *(const short8*)(Blo_g + (size_t)n * HID + go);
            }
            *(short8*)(Bh + row * LDK + kq * 8) = vh;
            *(short8*)(Bl + row * LDK + kq * 8) = vl;
        }
        __syncthreads();

        short8 af_h[4], af_l[4], bf_h[4], bf_l[4];
        #pragma unroll
        for (int i = 0; i < 4; ++i) {
            const int r = wr * 64 + i * 16 + col;
            af_h[i] = *(const short8*)(Ah + r * LDK + kg * 8);
            af_l[i] = *(const short8*)(Al + r * LDK + kg * 8);
        }
        #pragma unroll
        for (int jt = 0; jt < 4; ++jt) {
            const int r = wc * 64 + jt * 16 + col;
            bf_h[jt] = *(const short8*)(Bh + r * LDK + kg * 8);
            bf_l[jt] = *(const short8*)(Bl + r * LDK + kg * 8);
        }
        #pragma unroll
        for (int i = 0; i < 4; ++i)
            #pragma unroll
            for (int jt = 0; jt < 4; ++jt) {
                acc[i][jt] = __builtin_amdgcn_mfma_f32_16x16x32_bf16(af_h[i], bf_h[jt], acc[i][jt], 0, 0, 0);
                acc[i][jt] = __builtin_amdgcn_mfma_f32_16x16x32_bf16(af_h[i], bf_l[jt], acc[i][jt], 0, 0, 0);
                acc[i][jt] = __builtin_amdgcn_mfma_f32_16x16x32_bf16(af_l[i], bf_h[jt], acc[i][jt], 0, 0, 0);
            }
    }

    #pragma unroll
    for (int i = 0; i < 4; ++i)
        #pragma unroll
        for (int jt = 0; jt < 4; ++jt)
            #pragma unroll
            for (int r = 0; r < 4; ++r) {
                const int m = m0 + wr * 64 + i * 16 + kg * 4 + r;
                const int n = n0 + wc * 64 + jt * 16 + col;
                if (n < VOCAB)
                    C[(size_t)m * VOCAB + n] = acc[i][jt][r] + bias[n];
            }
}

extern "C" void kernel_launch(void* const* d_in, const int* in_sizes, int n_in,
                              void* d_out, int out_size, void* d_ws, size_t ws_size,
                              hipStream_t stream) {
    const int*   inputs = (const int*)d_in[0];
    const float* h0     = (const float*)d_in[1];
    const float* W_ih   = (const float*)d_in[2];
    const float* W_hh   = (const float*)d_in[3];
    const float* b_ih   = (const float*)d_in[4];
    const float* b_hh   = (const float*)d_in[5];
    const float* W_out  = (const float*)d_in[6];
    const float* b_out  = (const float*)d_in[7];
    float* out = (float*)d_out;

    // workspace layout
    char* p = (char*)d_ws;
    unsigned short* ghi     = (unsigned short*)p; p += (size_t)(SEQ + 1) * HSLICE * 2;
    unsigned short* glo     = (unsigned short*)p; p += (size_t)(SEQ + 1) * HSLICE * 2;
    unsigned short* whh_hi  = (unsigned short*)p; p += (size_t)3 * HID * HID * 2;
    unsigned short* whh_lo  = (unsigned short*)p; p += (size_t)3 * HID * HID * 2;
    unsigned short* wout_hi = (unsigned short*)p; p += (size_t)VOCAB * HID * 2;
    unsigned short* wout_lo = (unsigned short*)p; p += (size_t)VOCAB * HID * 2;
    float* W_ihT            = (float*)p;          p += (size_t)VOCAB * H3 * 4;
    int* bar                = (int*)p;            p += 8192 * 4;

    split_kernel<<<2048, 256, 0, stream>>>(W_hh, W_out, h0,
        whh_hi, whh_lo, wout_hi, wout_lo, ghi /*slice 0*/, glo /*slice 0*/);
    transpose_wih<<<dim3(VOCAB / 32, H3 / 32), 256, 0, stream>>>(W_ih, W_ihT);
    zero_barrier<<<8, 1024, 0, stream>>>(bar);

    float* hn_out = out + (size_t)SEQ * BATCH * VOCAB;
    const unsigned short* a_whh_hi = whh_hi;
    const unsigned short* a_whh_lo = whh_lo;
    const float* a_wihT = W_ihT;
    const float* a_bih = b_ih;
    const float* a_bhh = b_hh;
    const float* a_h0 = h0;
    const int* a_ids = inputs;
    unsigned short* a_ghi = ghi;
    unsigned short* a_glo = glo;
    int* a_bar = bar;
    void* kargs[] = { (void*)&a_whh_hi, (void*)&a_whh_lo, (void*)&a_wihT,
                      (void*)&a_bih, (void*)&a_bhh, (void*)&a_h0, (void*)&a_ids,
                      (void*)&a_ghi, (void*)&a_glo, (void*)&hn_out, (void*)&a_bar };
    hipLaunchCooperativeKernel((const void*)gru_persist, dim3(128), dim3(1024),
                               kargs, 0, stream);

    out_gemm_mfma<<<4096, 256, 0, stream>>>(
        ghi + HSLICE, glo + HSLICE, wout_hi, wout_lo, b_out, out);
}

// Round 12
// 1769.674 us; speedup vs baseline: 1.4720x; 1.4720x over previous
//
#include <hip/hip_runtime.h>
#include <math.h>

#define SEQ 256
#define BATCH 64
#define HID 1024
#define VOCAB 4000
#define H3 (3 * HID)
#define HSLICE (BATCH * HID)

typedef __attribute__((ext_vector_type(8))) short short8;
typedef __attribute__((ext_vector_type(4))) float f32x4;

__device__ inline unsigned short f2bf(float x) {
    unsigned int u = __builtin_bit_cast(unsigned int, x);
    unsigned int r = (u + 0x7fffu + ((u >> 16) & 1u)) >> 16;   // RNE
    return (unsigned short)r;
}
__device__ inline float bf2f(unsigned short h) {
    unsigned int u = ((unsigned int)h) << 16;
    return __builtin_bit_cast(float, u);
}

// ---------------------------------------------------------------------------
// Split f32 arrays into bf16 hi/lo pairs. h0 goes into slice 0 of the
// h-history (so the persistent kernel has no t==0 special case).
// ---------------------------------------------------------------------------
__global__ __launch_bounds__(256) void split_kernel(
    const float* __restrict__ W_hh, const float* __restrict__ W_out,
    const float* __restrict__ h0,
    unsigned short* __restrict__ whh_hi, unsigned short* __restrict__ whh_lo,
    unsigned short* __restrict__ wout_hi, unsigned short* __restrict__ wout_lo,
    unsigned short* __restrict__ h0_hi, unsigned short* __restrict__ h0_lo)
{
    const int NW = 3 * HID * HID;
    const int NO = VOCAB * HID;
    const int NH = BATCH * HID;
    const int total = NW + NO + NH;
    for (int i = blockIdx.x * blockDim.x + threadIdx.x; i < total;
         i += gridDim.x * blockDim.x) {
        const float* src; unsigned short *dh, *dl; int off;
        if (i < NW)           { src = W_hh;  dh = whh_hi;  dl = whh_lo;  off = i; }
        else if (i < NW + NO) { src = W_out; dh = wout_hi; dl = wout_lo; off = i - NW; }
        else                  { src = h0;    dh = h0_hi;   dl = h0_lo;   off = i - NW - NO; }
        float x = src[off];
        unsigned short hi = f2bf(x);
        dh[off] = hi;
        dl[off] = f2bf(x - bf2f(hi));
    }
}

// ---------------------------------------------------------------------------
// W_ih (3072 x 4000) -> W_ihT (4000 x 3072), 32x32 LDS tiles.
// ---------------------------------------------------------------------------
__global__ __launch_bounds__(256) void transpose_wih(
    const float* __restrict__ W_ih, float* __restrict__ W_ihT)
{
    __shared__ float tile[32][33];
    const int tx = threadIdx.x & 31;
    const int ty = threadIdx.x >> 5;          // 0..7
    const int r0 = blockIdx.y * 32;           // 3072-dim base
    const int c0 = blockIdx.x * 32;           // 4000-dim base
    #pragma unroll
    for (int k = 0; k < 4; ++k) {
        const int r = ty + k * 8;
        tile[r][tx] = W_ih[(size_t)(r0 + r) * VOCAB + c0 + tx];  // 4000%32==0
    }
    __syncthreads();
    #pragma unroll
    for (int k = 0; k < 4; ++k) {
        const int r = ty + k * 8;
        W_ihT[(size_t)(c0 + r) * H3 + r0 + tx] = tile[tx][r];
    }
}

__global__ void zero_barrier(int* b) {                    // 32768 ints (128 KB)
    b[blockIdx.x * 1024 + threadIdx.x] = 0;
}

// ---------------------------------------------------------------------------
// Persistent cooperative GRU: 256 blocks x 512 threads (8 waves, 1 block/CU).
// Block (jt, mt) as in round 10; 8-way K-split (K=128/wave, 24 weight short8
// register-hoisted = 96 VGPR). Per step: ONE __syncthreads only.
//   - LDS reduce scratch double-buffered by step parity (red[2][..]) so no
//     trailing barrier is needed for reuse.
//   - publish is PER-WAVE: each epilogue wave WT-stores its h outputs
//     (agent-scope packed u32, write-through to LLC), waits its own
//     vmcnt(0), then stores its own flag[jt][mt][ew] = t+1. No block-wide
//     drain, no fence, flags go out one barrier earlier than round 10.
//   - x_proj prefetch for t+1 issues AFTER the flag store (off the publish
//     path; retired by the next step's syncthreads).
// Consumer wave w polls 32 per-wave flags (8 producer j-tiles x 4 epilogue
// waves, lanes 0-31). Flags monotone; zeroed once per launch.
// ---------------------------------------------------------------------------
__global__ __launch_bounds__(512) void gru_persist(
    const unsigned short* __restrict__ whh_hi,
    const unsigned short* __restrict__ whh_lo,
    const float* __restrict__ W_ihT,
    const float* __restrict__ b_ih,
    const float* __restrict__ b_hh,
    const float* __restrict__ h0,
    const int* __restrict__ ids,
    unsigned short* ghi,                 // (SEQ+1) slices of 64x1024
    unsigned short* glo,
    float* hn_out,                       // d_out tail (64x1024)
    int* flag)                           // 1024 flags, stride 32 ints
{
    __shared__ f32x4 red[2][8][3][65];   // parity-double-buffered, ~50 KB

    const int tid = threadIdx.x;
    const int w   = tid >> 6;            // 0..7 (K-split)
    const int l   = tid & 63;
    const int bid = blockIdx.x;
    const int grp   = bid & 7;           // XCD (round-robin dispatch)
    const int local = bid >> 3;          // 0..31
    const int jt  = grp * 8 + (local >> 2);
    const int mt  = local & 3;
    const int j0  = jt * 16;
    const int m0  = mt * 16;
    const int col = l & 15, kg = l >> 4;

    const size_t arow   = (size_t)(m0 + col) * HID;
    const size_t brow_r = (size_t)(j0 + col) * HID;
    const size_t brow_z = (size_t)(HID + j0 + col) * HID;
    const size_t brow_n = (size_t)(2 * HID + j0 + col) * HID;
    const int kbase = w * 128 + kg * 8;

    // ---- hoist this wave's weight fragments into registers (96 VGPRs) ----
    short8 wr_h[4], wr_l[4], wz_h[4], wz_l[4], wn_h[4], wn_l[4];
    #pragma unroll
    for (int c = 0; c < 4; ++c) {
        const int ko = kbase + c * 32;
        wr_h[c] = *(const short8*)(whh_hi + brow_r + ko);
        wr_l[c] = *(const short8*)(whh_lo + brow_r + ko);
        wz_h[c] = *(const short8*)(whh_hi + brow_z + ko);
        wz_l[c] = *(const short8*)(whh_lo + brow_z + ko);
        wn_h[c] = *(const short8*)(whh_hi + brow_n + ko);
        wn_l[c] = *(const short8*)(whh_lo + brow_n + ko);
    }

    // epilogue persistent state: tid<256, 1 thread = 1 output (b, j)
    const int bi = tid >> 4;             // valid for tid<256: 0..15
    const int cj = tid & 15;
    const int eb = m0 + (bi & 15), ej = j0 + cj;
    float hreg = 0.f, xr_n = 0.f, xz_n = 0.f, xn_n = 0.f;
    float bihr = 0.f, bihz = 0.f, bihn = 0.f;
    float bhhr = 0.f, bhhz = 0.f, bhhn = 0.f;
    if (tid < 256) {
        hreg = h0[(size_t)eb * HID + ej];
        bihr = b_ih[ej]; bihz = b_ih[HID + ej]; bihn = b_ih[2 * HID + ej];
        bhhr = b_hh[ej]; bhhz = b_hh[HID + ej]; bhhn = b_hh[2 * HID + ej];
        const int id0 = ids[eb * SEQ];
        const float* xrow = W_ihT + (size_t)id0 * H3;
        xr_n = xrow[ej]; xz_n = xrow[HID + ej]; xn_n = xrow[2 * HID + ej];
    }
    const int lane = ((bi & 15) >> 2) * 16 + cj;   // MFMA C-layout inverse
    const int reg  = bi & 3;

    // per-wave flags: index ((jt*4+mt)*4 + epilogue_wave)*32
    const int myflag = ((jt * 4 + mt) * 4 + w) * 32;        // used by waves 0-3
    const int pollfl = (((w * 8 + (l >> 2)) * 4 + mt) * 4 + (l & 3)) * 32;

    for (int t = 0; t < SEQ; ++t) {
        // ---- dataflow wait: 8 producer blocks x 4 epilogue waves ----
        if (t > 0) {
            if (l < 32) {
                while (__hip_atomic_load(&flag[pollfl], __ATOMIC_RELAXED,
                                         __HIP_MEMORY_SCOPE_AGENT) < t)
                    __builtin_amdgcn_s_sleep(1);
            }
            asm volatile("" ::: "memory");   // no load hoisting above polls
        }

        const unsigned short* ah = ghi + (size_t)t * HSLICE;   // h_{t-1}
        const unsigned short* al = glo + (size_t)t * HSLICE;

        f32x4 accr = {0.f, 0.f, 0.f, 0.f};
        f32x4 accz = {0.f, 0.f, 0.f, 0.f};
        f32x4 accn = {0.f, 0.f, 0.f, 0.f};

        #pragma unroll
        for (int c = 0; c < 4; ++c) {
            const int ko = kbase + c * 32;
            short8 a_h = *(const short8*)(ah + arow + ko);
            short8 a_l = *(const short8*)(al + arow + ko);

            accr = __builtin_amdgcn_mfma_f32_16x16x32_bf16(a_h, wr_h[c], accr, 0, 0, 0);
            accr = __builtin_amdgcn_mfma_f32_16x16x32_bf16(a_h, wr_l[c], accr, 0, 0, 0);
            accr = __builtin_amdgcn_mfma_f32_16x16x32_bf16(a_l, wr_h[c], accr, 0, 0, 0);

            accz = __builtin_amdgcn_mfma_f32_16x16x32_bf16(a_h, wz_h[c], accz, 0, 0, 0);
            accz = __builtin_amdgcn_mfma_f32_16x16x32_bf16(a_h, wz_l[c], accz, 0, 0, 0);
            accz = __builtin_amdgcn_mfma_f32_16x16x32_bf16(a_l, wz_h[c], accz, 0, 0, 0);

            accn = __builtin_amdgcn_mfma_f32_16x16x32_bf16(a_h, wn_h[c], accn, 0, 0, 0);
            accn = __builtin_amdgcn_mfma_f32_16x16x32_bf16(a_h, wn_l[c], accn, 0, 0, 0);
            accn = __builtin_amdgcn_mfma_f32_16x16x32_bf16(a_l, wn_h[c], accn, 0, 0, 0);
        }

        const int par = t & 1;
        red[par][w][0][l] = accr;
        red[par][w][1][l] = accz;
        red[par][w][2][l] = accn;
        __syncthreads();                 // the ONLY barrier this step

        if (tid < 256) {
            float sr = 0.f, sz = 0.f, sn = 0.f;
            #pragma unroll
            for (int kk = 0; kk < 8; ++kk) {
                sr += ((const float*)&red[par][kk][0][lane])[reg];
                sz += ((const float*)&red[par][kk][1][lane])[reg];
                sn += ((const float*)&red[par][kk][2][lane])[reg];
            }
            const float xr = xr_n + bihr;
            const float xz = xz_n + bihz;
            const float xn = xn_n + bihn;
            const float rg = 1.f / (1.f + expf(-(xr + sr + bhhr)));
            const float zg = 1.f / (1.f + expf(-(xz + sz + bhhz)));
            const float ng = tanhf(xn + rg * (sn + bhhn));
            hreg = (1.f - zg) * ng + zg * hreg;

            // ---- h store: packed u32, agent-scope write-through ----
            const unsigned short hh = f2bf(hreg);
            const unsigned short ll = f2bf(hreg - bf2f(hh));
            const unsigned int hh_n = (unsigned int)(unsigned short)
                __shfl_xor((int)hh, 1, 64);
            const unsigned int ll_n = (unsigned int)(unsigned short)
                __shfl_xor((int)ll, 1, 64);
            const size_t ho = (size_t)(t + 1) * HSLICE + (size_t)eb * HID + ej;
            if ((cj & 1) == 0) {
                const unsigned int hp = (unsigned int)hh | (hh_n << 16);
                const unsigned int lp = (unsigned int)ll | (ll_n << 16);
                __hip_atomic_store((unsigned int*)ghi + (ho >> 1), hp,
                                   __ATOMIC_RELAXED, __HIP_MEMORY_SCOPE_AGENT);
                __hip_atomic_store((unsigned int*)glo + (ho >> 1), lp,
                                   __ATOMIC_RELAXED, __HIP_MEMORY_SCOPE_AGENT);
            }
            // per-wave publish: wait own stores, then own flag
            asm volatile("s_waitcnt vmcnt(0)" ::: "memory");
            if (l == 0) {
                __hip_atomic_store(&flag[myflag], t + 1, __ATOMIC_RELAXED,
                                   __HIP_MEMORY_SCOPE_AGENT);
            }
            // prefetch next x_proj row AFTER publish (off the critical path)
            if (t + 1 < SEQ) {
                const int id2 = ids[eb * SEQ + t + 1];
                const float* xrow = W_ihT + (size_t)id2 * H3;
                xr_n = xrow[ej]; xz_n = xrow[HID + ej]; xn_n = xrow[2 * HID + ej];
            } else {
                hn_out[(size_t)eb * HID + ej] = hreg;
            }
        }
        // no trailing barrier: red[] is parity-double-buffered, and next
        // step's syncthreads orders everything else.
    }
}

// ---------------------------------------------------------------------------
// Output GEMM, split-bf16 MFMA. 1D grid 4096 blocks, XCD-aware stripes.
// ---------------------------------------------------------------------------
__global__ __launch_bounds__(256) void out_gemm_mfma(
    const unsigned short* __restrict__ Ahi_g,  // 16384 x 1024
    const unsigned short* __restrict__ Alo_g,
    const unsigned short* __restrict__ Bhi_g,  // 4000 x 1024
    const unsigned short* __restrict__ Blo_g,
    const float* __restrict__ bias,
    float* __restrict__ C)
{
    constexpr int BM = 128, BK = 32, LDK = 40;
    __shared__ unsigned short Ah[BM * LDK], Al[BM * LDK];
    __shared__ unsigned short Bh[BM * LDK], Bl[BM * LDK];

    const int tid = threadIdx.x;
    const int l = tid & 63, w = tid >> 6;
    const int wr = w >> 1, wc = w & 1;
    const int col = l & 15, kg = l >> 4;
    const int bid = blockIdx.x;
    const int xcd = bid & 7;
    const int q   = bid >> 3;
    const int yb  = xcd * 4 + (q >> 7);       // 0..31 (n-tile)
    const int xb  = q & 127;                  // 0..127 (m-tile)
    const int m0 = xb * BM;
    const int n0 = yb * BM;

    f32x4 acc[4][4];
    #pragma unroll
    for (int i = 0; i < 4; ++i)
        #pragma unroll
        for (int jt = 0; jt < 4; ++jt)
            acc[i][jt] = (f32x4){0.f, 0.f, 0.f, 0.f};

    for (int kc = 0; kc < HID; kc += BK) {
        __syncthreads();
        #pragma unroll
        for (int i = 0; i < 2; ++i) {
            const int idx = tid + i * 256;          // 0..511
            const int row = idx >> 2, kq = idx & 3;
            const int go = kc + kq * 8;
            *(short8*)(Ah + row * LDK + kq * 8) =
                *(const short8*)(Ahi_g + (size_t)(m0 + row) * HID + go);
            *(short8*)(Al + row * LDK + kq * 8) =
                *(const short8*)(Alo_g + (size_t)(m0 + row) * HID + go);
            const int n = n0 + row;
            short8 vh = {0,0,0,0,0,0,0,0}, vl = {0,0,0,0,0,0,0,0};
            if (n < VOCAB) {
                vh = *(const short8*)(Bhi_g + (size_t)n * HID + go);
                vl = *(const short8*)(Blo_g + (size_t)n * HID + go);
            }
            *(short8*)(Bh + row * LDK + kq * 8) = vh;
            *(short8*)(Bl + row * LDK + kq * 8) = vl;
        }
        __syncthreads();

        short8 af_h[4], af_l[4], bf_h[4], bf_l[4];
        #pragma unroll
        for (int i = 0; i < 4; ++i) {
            const int r = wr * 64 + i * 16 + col;
            af_h[i] = *(const short8*)(Ah + r * LDK + kg * 8);
            af_l[i] = *(const short8*)(Al + r * LDK + kg * 8);
        }
        #pragma unroll
        for (int jt = 0; jt < 4; ++jt) {
            const int r = wc * 64 + jt * 16 + col;
            bf_h[jt] = *(const short8*)(Bh + r * LDK + kg * 8);
            bf_l[jt] = *(const short8*)(Bl + r * LDK + kg * 8);
        }
        #pragma unroll
        for (int i = 0; i < 4; ++i)
            #pragma unroll
            for (int jt = 0; jt < 4; ++jt) {
                acc[i][jt] = __builtin_amdgcn_mfma_f32_16x16x32_bf16(af_h[i], bf_h[jt], acc[i][jt], 0, 0, 0);
                acc[i][jt] = __builtin_amdgcn_mfma_f32_16x16x32_bf16(af_h[i], bf_l[jt], acc[i][jt], 0, 0, 0);
                acc[i][jt] = __builtin_amdgcn_mfma_f32_16x16x32_bf16(af_l[i], bf_h[jt], acc[i][jt], 0, 0, 0);
            }
    }

    #pragma unroll
    for (int i = 0; i < 4; ++i)
        #pragma unroll
        for (int jt = 0; jt < 4; ++jt)
            #pragma unroll
            for (int r = 0; r < 4; ++r) {
                const int m = m0 + wr * 64 + i * 16 + kg * 4 + r;
                const int n = n0 + wc * 64 + jt * 16 + col;
                if (n < VOCAB)
                    C[(size_t)m * VOCAB + n] = acc[i][jt][r] + bias[n];
            }
}

extern "C" void kernel_launch(void* const* d_in, const int* in_sizes, int n_in,
                              void* d_out, int out_size, void* d_ws, size_t ws_size,
                              hipStream_t stream) {
    const int*   inputs = (const int*)d_in[0];
    const float* h0     = (const float*)d_in[1];
    const float* W_ih   = (const float*)d_in[2];
    const float* W_hh   = (const float*)d_in[3];
    const float* b_ih   = (const float*)d_in[4];
    const float* b_hh   = (const float*)d_in[5];
    const float* W_out  = (const float*)d_in[6];
    const float* b_out  = (const float*)d_in[7];
    float* out = (float*)d_out;

    // workspace layout
    char* p = (char*)d_ws;
    unsigned short* ghi     = (unsigned short*)p; p += (size_t)(SEQ + 1) * HSLICE * 2;
    unsigned short* glo     = (unsigned short*)p; p += (size_t)(SEQ + 1) * HSLICE * 2;
    unsigned short* whh_hi  = (unsigned short*)p; p += (size_t)3 * HID * HID * 2;
    unsigned short* whh_lo  = (unsigned short*)p; p += (size_t)3 * HID * HID * 2;
    unsigned short* wout_hi = (unsigned short*)p; p += (size_t)VOCAB * HID * 2;
    unsigned short* wout_lo = (unsigned short*)p; p += (size_t)VOCAB * HID * 2;
    float* W_ihT            = (float*)p;          p += (size_t)VOCAB * H3 * 4;
    int* bar                = (int*)p;            p += 32768 * 4;   // 128 KB flags

    split_kernel<<<2048, 256, 0, stream>>>(W_hh, W_out, h0,
        whh_hi, whh_lo, wout_hi, wout_lo, ghi /*slice 0*/, glo /*slice 0*/);
    transpose_wih<<<dim3(VOCAB / 32, H3 / 32), 256, 0, stream>>>(W_ih, W_ihT);
    zero_barrier<<<32, 1024, 0, stream>>>(bar);

    float* hn_out = out + (size_t)SEQ * BATCH * VOCAB;
    const unsigned short* a_whh_hi = whh_hi;
    const unsigned short* a_whh_lo = whh_lo;
    const float* a_wihT = W_ihT;
    const float* a_bih = b_ih;
    const float* a_bhh = b_hh;
    const float* a_h0 = h0;
    const int* a_ids = inputs;
    unsigned short* a_ghi = ghi;
    unsigned short* a_glo = glo;
    int* a_bar = bar;
    void* kargs[] = { (void*)&a_whh_hi, (void*)&a_whh_lo, (void*)&a_wihT,
                      (void*)&a_bih, (void*)&a_bhh, (void*)&a_h0, (void*)&a_ids,
                      (void*)&a_ghi, (void*)&a_glo, (void*)&hn_out, (void*)&a_bar };
    hipLaunchCooperativeKernel((const void*)gru_persist, dim3(256), dim3(512),
                               kargs, 0, stream);

    out_gemm_mfma<<<4096, 256, 0, stream>>>(
        ghi + HSLICE, glo + HSLICE, wout_hi, wout_lo, b_out, out);
}